// Round 1
// baseline (208.233 us; speedup 1.0000x reference)
//
#include <hip/hip_runtime.h>

// MHA forward: B=2, T=2048, DIM=1024, NH=16, HD=64
// [convX, convT x2]  -> ws{Xb bf16 [M][K], Wqkv^T bf16 [3072][1024], Wproj^T bf16 [1024][1024]}
// [qkv GEMM 2-phase dbuf + RoPE, LDS-transpose V epilogue] -> ws{Q,K bf16 [B,NH,T,HD], V^T bf16 [B,NH,HD,T]}
// [flash attn, LDS dbuf] -> ws{Y bf16 [B,T,DIM]}
// [proj GEMM 2-phase dbuf] -> d_out fp32

typedef float  f32x4  __attribute__((ext_vector_type(4)));
typedef __bf16 bf16x8 __attribute__((ext_vector_type(8)));
typedef short  short8 __attribute__((ext_vector_type(8)));

#define Bb   2
#define Tt   2048
#define DIMc 1024
#define NHh  16
#define HDd  64

__device__ __forceinline__ short f2bf(float f) {
    unsigned u = __builtin_bit_cast(unsigned, f);
    u += 0x7fffu + ((u >> 16) & 1u);          // RNE
    return (short)(u >> 16);
}

__device__ __forceinline__ f32x4 mfma16(short8 a, short8 b, f32x4 c) {
    return __builtin_amdgcn_mfma_f32_16x16x32_bf16(
        __builtin_bit_cast(bf16x8, a), __builtin_bit_cast(bf16x8, b), c, 0, 0, 0);
}

__device__ __forceinline__ void gl_lds16(const void* g, void* l) {
    __builtin_amdgcn_global_load_lds(
        (const __attribute__((address_space(1))) unsigned int*)g,
        (__attribute__((address_space(3))) unsigned int*)l, 16, 0, 0);
}

// ---------------------------------------------------------------------------
// convX: fp32 -> bf16 elementwise, 8 elems/thread.
// ---------------------------------------------------------------------------
__global__ __launch_bounds__(256) void convX(const float* __restrict__ X,
                                             short* __restrict__ Xb)
{
    size_t i = ((size_t)blockIdx.x * 256 + threadIdx.x) * 8;
    float4 a = *(const float4*)(X + i);
    float4 b = *(const float4*)(X + i + 4);
    short8 s;
    s[0] = f2bf(a.x); s[1] = f2bf(a.y); s[2] = f2bf(a.z); s[3] = f2bf(a.w);
    s[4] = f2bf(b.x); s[5] = f2bf(b.y); s[6] = f2bf(b.z); s[7] = f2bf(b.w);
    *(short8*)(Xb + i) = s;
}

// ---------------------------------------------------------------------------
// convT: W fp32 [K=1024][N] -> Wt bf16 [N][1024]. 64x64 LDS tile transpose.
// ---------------------------------------------------------------------------
__global__ __launch_bounds__(256) void convT(const float* __restrict__ W,
                                             short* __restrict__ Wt, int N)
{
    __shared__ float L[64][65];
    const int kb = blockIdx.x * 64, nb = blockIdx.y * 64;
    const int tid = threadIdx.x;
#pragma unroll
    for (int it = 0; it < 4; it++) {
        int kk = it * 16 + (tid >> 4), c = (tid & 15) * 4;
        float4 v = *(const float4*)(W + (size_t)(kb + kk) * N + nb + c);
        L[c + 0][kk] = v.x; L[c + 1][kk] = v.y;
        L[c + 2][kk] = v.z; L[c + 3][kk] = v.w;
    }
    __syncthreads();
#pragma unroll
    for (int it = 0; it < 2; it++) {
        int n = it * 32 + (tid >> 3), ks = (tid & 7) * 8;
        short8 s;
#pragma unroll
        for (int j = 0; j < 8; j++) s[j] = f2bf(L[n][ks + j]);
        *(short8*)(Wt + (size_t)(nb + n) * 1024 + kb + ks) = s;
    }
}

// ---------------------------------------------------------------------------
// qkv GEMM: C = Xb @ Wqkv (via Wt [3072][1024]), M=4096,N=3072,K=1024.
// 2-phase double-buffered pipeline: stage(t+1) issued BEFORE compute(t),
// ONE barrier per K-step (T3-minimum recipe). Fused RoPE epilogue for Q/K;
// V (block-uniform bn>=16) transposed through LDS -> coalesced stores.
// ---------------------------------------------------------------------------
__global__ __launch_bounds__(256) void qkv_rope(
    const short* __restrict__ A, const short* __restrict__ Bt,
    const float* __restrict__ Sn, const float* __restrict__ Cs,
    short* __restrict__ Qo, short* __restrict__ Ko, short* __restrict__ Vt)
{
    __shared__ __align__(16) short As[2][128][32];
    __shared__ __align__(16) short Bs[2][128][32];
    const int bm = blockIdx.x, bn = blockIdx.y;
    const int tid = threadIdx.x;
    const int wv = tid >> 6, lane = tid & 63, g = lane >> 4, l16 = lane & 15;
    const int wr = wv >> 1, wc = wv & 1;

    f32x4 acc[4][4];
#pragma unroll
    for (int i = 0; i < 4; i++)
#pragma unroll
        for (int j = 0; j < 4; j++) acc[i][j] = (f32x4){0.f, 0.f, 0.f, 0.f};

    const int rA = tid >> 2, cA = (tid & 3) << 3;     // staging coords (per 256-chunk)
    const short* pA = A  + (size_t)(bm * 128 + rA) * 1024 + cA;
    const short* pB = Bt + (size_t)(bn * 128 + rA) * 1024 + cA;

    auto stage = [&](int k0, int b) {
        gl_lds16(pA + k0,             &As[b][rA][cA]);
        gl_lds16(pA + k0 + 64 * 1024, &As[b][64 + rA][cA]);
        gl_lds16(pB + k0,             &Bs[b][rA][cA]);
        gl_lds16(pB + k0 + 64 * 1024, &Bs[b][64 + rA][cA]);
    };

    stage(0, 0);
    __syncthreads();                         // drains vmcnt(0): buf0 ready
    int buf = 0;
    for (int k0 = 0; k0 < 1024; k0 += 32) {
        if (k0 + 32 < 1024) stage(k0 + 32, buf ^ 1);   // prefetch next K-tile
        short8 af[4], bfr[4];
#pragma unroll
        for (int mt = 0; mt < 4; mt++) af[mt]  = *(const short8*)&As[buf][wr * 64 + mt * 16 + l16][g * 8];
#pragma unroll
        for (int nt = 0; nt < 4; nt++) bfr[nt] = *(const short8*)&Bs[buf][wc * 64 + nt * 16 + l16][g * 8];
#pragma unroll
        for (int mt = 0; mt < 4; mt++)
#pragma unroll
            for (int nt = 0; nt < 4; nt++) acc[mt][nt] = mfma16(af[mt], bfr[nt], acc[mt][nt]);
        __syncthreads();                     // vmcnt(0)+lgkmcnt(0) drain: buf^1 ready
        buf ^= 1;
    }

    if (bn >= 16) {
        // --------- V blocks: transpose 128(m) x 128(n) through LDS ---------
        // T[32][136] bf16 (8.5 KB) aliases As (16 KB). Pad 136 -> row stride
        // 272 B = bank shift 4 -> scalar writes only 2-way conflicted (free).
        short (*T)[136] = (short(*)[136])&As[0][0][0];
        const int b  = bm >> 4;                  // (bm*128)>>11, uniform per block
        const int t0 = (bm * 128) & 2047;
        const int nbase = (bn - 16) * 128;       // offset within V's 1024 cols
#pragma unroll
        for (int ch = 0; ch < 4; ++ch) {
            __syncthreads();                     // prev chunk's reads done
            if (wc == (ch >> 1)) {
#pragma unroll
                for (int ntl = 0; ntl < 2; ++ntl) {
                    int nt = (ch & 1) * 2 + ntl;
#pragma unroll
                    for (int mt = 0; mt < 4; ++mt)
#pragma unroll
                        for (int r = 0; r < 4; ++r)
                            T[ntl * 16 + l16][wr * 64 + mt * 16 + g * 4 + r] =
                                f2bf(acc[mt][nt][r]);
                }
            }
            __syncthreads();
            // 32 rows x 128 cols, 256 threads -> 16 shorts (32 B) each, coalesced
            int row = tid >> 3, c8 = (tid & 7) * 16;
            int nn = nbase + ch * 32 + row;
            int h = nn >> 6, d = nn & 63;
            short8 v0 = *(const short8*)&T[row][c8];
            short8 v1 = *(const short8*)&T[row][c8 + 8];
            size_t base = (((size_t)(b * 16 + h) * 64 + d) << 11) + t0 + c8;
            *(short8*)(Vt + base)     = v0;
            *(short8*)(Vt + base + 8) = v1;
        }
    } else {
        // --------- Q/K blocks: RoPE epilogue (unchanged) ---------
#pragma unroll
        for (int mt = 0; mt < 4; mt++)
#pragma unroll
            for (int nt = 0; nt < 4; nt++)
#pragma unroll
                for (int r = 0; r < 4; r++) {
                    int m = bm * 128 + wr * 64 + mt * 16 + g * 4 + r;
                    int n = bn * 128 + wc * 64 + nt * 16 + l16;
                    float val = acc[mt][nt][r];
                    float partner = __shfl_xor(val, 1, 64);
                    int b = m >> 11, t = m & 2047;
                    int sec = n >> 10, nn = n & 1023;
                    int h = nn >> 6, d = nn & 63;
                    float sv = Sn[t * 64 + d], cv = Cs[t * 64 + d];
                    float ro = (d & 1) ? fmaf(val, cv, partner * sv)
                                       : fmaf(val, cv, -partner * sv);
                    short* dst = (sec == 0) ? Qo : Ko;
                    dst[(((size_t)(b * 16 + h) << 11) + t) * 64 + d] = f2bf(ro);
                }
    }
}

// ---------------------------------------------------------------------------
// Kernel 2: causal flash attention (unchanged — verified).
// ---------------------------------------------------------------------------
__global__ __launch_bounds__(256, 4) void attn(
    const short* __restrict__ Q, const short* __restrict__ K,
    const short* __restrict__ V, short* __restrict__ Y)
{
    __shared__ __align__(16) short Ks[2][64][64];
    __shared__ __align__(16) short Vs[2][64][64];
    __shared__ __align__(16) short Pl[4][16][64];

    const int id = blockIdx.y * gridDim.x + blockIdx.x;
    const int bh = id >> 5;
    const int qi = ((id & 31) + ((id >> 8) << 3)) & 31;
    const int tid = threadIdx.x, wv = tid >> 6, lane = tid & 63;
    const int g = lane >> 4, l16 = lane & 15;
    const int q0w = qi * 64 + wv * 16;
    const short* Qb = Q + (size_t)bh * Tt * 64;
    const short* Kb = K + (size_t)bh * Tt * 64;
    const short* Vb = V + (size_t)bh * 64 * Tt;

    const int rj = lane >> 3, cc = lane & 7, gc = cc ^ rj;

    auto stage = [&](int s, int buf) {
        int k0s = s * 64;
#pragma unroll
        for (int j = 0; j < 2; j++) {
            int row = wv * 16 + j * 8 + rj;
            gl_lds16(Kb + (size_t)(k0s + row) * 64 + gc * 8, &Ks[buf][row][cc << 3]);
        }
#pragma unroll
        for (int j = 0; j < 2; j++) {
            int row = wv * 16 + j * 8 + rj;
            gl_lds16(Vb + (size_t)row * Tt + k0s + gc * 8, &Vs[buf][row][cc << 3]);
        }
    };

    short8 qf[2];
#pragma unroll
    for (int ss = 0; ss < 2; ss++)
        qf[ss] = *(const short8*)(Qb + (size_t)(q0w + l16) * 64 + ss * 32 + g * 8);

    f32x4 o[4];
#pragma unroll
    for (int nt = 0; nt < 4; nt++) o[nt] = (f32x4){0.f, 0.f, 0.f, 0.f};
    float lsum[4] = {0.f, 0.f, 0.f, 0.f};

    const int nsteps = qi + 1;
    const int sw = l16 & 7;

    stage(0, 0);
    __syncthreads();

    for (int s = 0; s < nsteps; ++s) {
        if (s + 1 < nsteps) stage(s + 1, (s + 1) & 1);
        const int kb = s & 1, k0 = s * 64;

        f32x4 S[4];
#pragma unroll
        for (int t = 0; t < 4; t++) {
            S[t] = (f32x4){0.f, 0.f, 0.f, 0.f};
#pragma unroll
            for (int ss = 0; ss < 2; ss++) {
                short8 kf = *(const short8*)&Ks[kb][t * 16 + l16][((ss * 4 + g) ^ sw) << 3];
                S[t] = mfma16(qf[ss], kf, S[t]);
            }
        }

        float p[4][4];
        if (s < nsteps - 1) {
#pragma unroll
            for (int t = 0; t < 4; t++)
#pragma unroll
                for (int r = 0; r < 4; r++)
                    p[t][r] = __expf(fmaf(S[t][r], 0.125f, -10.f));
        } else {
#pragma unroll
            for (int t = 0; t < 4; t++)
#pragma unroll
                for (int r = 0; r < 4; r++) {
                    int key = k0 + t * 16 + l16, qq = q0w + g * 4 + r;
                    p[t][r] = (key <= qq) ? __expf(fmaf(S[t][r], 0.125f, -10.f)) : 0.f;
                }
        }
#pragma unroll
        for (int r = 0; r < 4; r++)
            lsum[r] += (p[0][r] + p[1][r]) + (p[2][r] + p[3][r]);

#pragma unroll
        for (int t = 0; t < 4; t++)
#pragma unroll
            for (int r = 0; r < 4; r++) {
                int row = g * 4 + r, c = t * 16 + l16;
                Pl[wv][row][(((c >> 3) ^ (row & 7)) << 3) | (c & 7)] = f2bf(p[t][r]);
            }
        asm volatile("" ::: "memory");
        short8 pf[2];
#pragma unroll
        for (int ks = 0; ks < 2; ks++)
            pf[ks] = *(const short8*)&Pl[wv][l16][((ks * 4 + g) ^ sw) << 3];
#pragma unroll
        for (int nt = 0; nt < 4; nt++)
#pragma unroll
            for (int ks = 0; ks < 2; ks++) {
                short8 vf = *(const short8*)&Vs[kb][nt * 16 + l16][((ks * 4 + g) ^ sw) << 3];
                o[nt] = mfma16(pf[ks], vf, o[nt]);
            }
        __syncthreads();
    }

    float inv[4];
#pragma unroll
    for (int r = 0; r < 4; r++) {
        float t = lsum[r];
        t += __shfl_xor(t, 1, 64);
        t += __shfl_xor(t, 2, 64);
        t += __shfl_xor(t, 4, 64);
        t += __shfl_xor(t, 8, 64);
        inv[r] = 1.0f / t;
    }
    const int b = bh >> 4, h = bh & 15;
#pragma unroll
    for (int nt = 0; nt < 4; nt++)
#pragma unroll
        for (int r = 0; r < 4; r++) {
            int qq = q0w + g * 4 + r, d = nt * 16 + l16;
            Y[((size_t)(b * Tt + qq)) * DIMc + h * 64 + d] = f2bf(o[nt][r] * inv[r]);
        }
}

// ---------------------------------------------------------------------------
// proj GEMM: out = Y @ Wproj (via Wt [1024][1024]), fp32 out.
// Same 2-phase double-buffered pipeline as qkv.
// ---------------------------------------------------------------------------
__global__ __launch_bounds__(256) void proj(
    const short* __restrict__ A, const short* __restrict__ Bt, float* __restrict__ O)
{
    __shared__ __align__(16) short As[2][128][32];
    __shared__ __align__(16) short Bs[2][128][32];
    const int bm = blockIdx.x, bn = blockIdx.y;
    const int tid = threadIdx.x;
    const int wv = tid >> 6, lane = tid & 63, g = lane >> 4, l16 = lane & 15;
    const int wr = wv >> 1, wc = wv & 1;

    f32x4 acc[4][4];
#pragma unroll
    for (int i = 0; i < 4; i++)
#pragma unroll
        for (int j = 0; j < 4; j++) acc[i][j] = (f32x4){0.f, 0.f, 0.f, 0.f};

    const int rA = tid >> 2, cA = (tid & 3) << 3;
    const short* pA = A  + (size_t)(bm * 128 + rA) * 1024 + cA;
    const short* pB = Bt + (size_t)(bn * 128 + rA) * 1024 + cA;

    auto stage = [&](int k0, int b) {
        gl_lds16(pA + k0,             &As[b][rA][cA]);
        gl_lds16(pA + k0 + 64 * 1024, &As[b][64 + rA][cA]);
        gl_lds16(pB + k0,             &Bs[b][rA][cA]);
        gl_lds16(pB + k0 + 64 * 1024, &Bs[b][64 + rA][cA]);
    };

    stage(0, 0);
    __syncthreads();
    int buf = 0;
    for (int k0 = 0; k0 < 1024; k0 += 32) {
        if (k0 + 32 < 1024) stage(k0 + 32, buf ^ 1);
        short8 af[4], bfr[4];
#pragma unroll
        for (int mt = 0; mt < 4; mt++) af[mt]  = *(const short8*)&As[buf][wr * 64 + mt * 16 + l16][g * 8];
#pragma unroll
        for (int nt = 0; nt < 4; nt++) bfr[nt] = *(const short8*)&Bs[buf][wc * 64 + nt * 16 + l16][g * 8];
#pragma unroll
        for (int mt = 0; mt < 4; mt++)
#pragma unroll
            for (int nt = 0; nt < 4; nt++) acc[mt][nt] = mfma16(af[mt], bfr[nt], acc[mt][nt]);
        __syncthreads();
        buf ^= 1;
    }

#pragma unroll
    for (int mt = 0; mt < 4; mt++)
#pragma unroll
        for (int nt = 0; nt < 4; nt++)
#pragma unroll
            for (int r = 0; r < 4; r++) {
                int m = bm * 128 + wr * 64 + mt * 16 + g * 4 + r;
                int n = bn * 128 + wc * 64 + nt * 16 + l16;
                O[(size_t)m * 1024 + n] = acc[mt][nt][r];
            }
}

// ---------------------------------------------------------------------------
extern "C" void kernel_launch(void* const* d_in, const int* in_sizes, int n_in,
                              void* d_out, int out_size, void* d_ws, size_t ws_size,
                              hipStream_t stream)
{
    const float* x     = (const float*)d_in[0];
    const float* sn    = (const float*)d_in[1];
    const float* cs    = (const float*)d_in[2];
    const float* wqkv  = (const float*)d_in[3];
    const float* wproj = (const float*)d_in[4];
    float* out = (float*)d_out;

    char* ws = (char*)d_ws;
    const size_t MB = 1024 * 1024;
    short* q   = (short*)(ws);            // 8 MB
    short* k   = (short*)(ws + 8  * MB);  // 8 MB
    short* vt  = (short*)(ws + 16 * MB);  // 8 MB
    short* y   = (short*)(ws + 24 * MB);  // 8 MB
    short* xb  = (short*)(ws + 32 * MB);  // 8 MB
    short* wqt = (short*)(ws + 40 * MB);  // 6 MB
    short* wpt = (short*)(ws + 46 * MB);  // 2 MB

    convX<<<2048, 256, 0, stream>>>(x, xb);
    convT<<<dim3(16, 48), 256, 0, stream>>>(wqkv, wqt, 3072);
    convT<<<dim3(16, 16), 256, 0, stream>>>(wproj, wpt, 1024);
    qkv_rope<<<dim3(32, 24), 256, 0, stream>>>(xb, wqt, sn, cs, q, k, vt);
    attn<<<dim3(Tt / 64, Bb * NHh), 256, 0, stream>>>(q, k, vt, y);
    proj<<<dim3(32, 8), 256, 0, stream>>>(y, wpt, out);
}

// Round 2
// 187.988 us; speedup vs baseline: 1.1077x; 1.1077x over previous
//
#include <hip/hip_runtime.h>

// MHA forward: B=2, T=2048, DIM=1024, NH=16, HD=64
// [convX, convT x2]  -> ws{Xb bf16 [M][K], Wqkv^T bf16 [3072][1024], Wproj^T bf16 [1024][1024]}
// [qkv GEMM 64x128xBK64, 6 blocks/CU, XOR-swizzled LDS + RoPE / V-transpose epilogue]
// [flash attn, LDS dbuf] -> ws{Y bf16 [B,T,DIM]}
// [proj GEMM 64x64xBK64, 4 blocks/CU] -> d_out fp32

typedef float  f32x4  __attribute__((ext_vector_type(4)));
typedef __bf16 bf16x8 __attribute__((ext_vector_type(8)));
typedef short  short8 __attribute__((ext_vector_type(8)));

#define Bb   2
#define Tt   2048
#define DIMc 1024
#define NHh  16
#define HDd  64

__device__ __forceinline__ short f2bf(float f) {
    unsigned u = __builtin_bit_cast(unsigned, f);
    u += 0x7fffu + ((u >> 16) & 1u);          // RNE
    return (short)(u >> 16);
}

__device__ __forceinline__ f32x4 mfma16(short8 a, short8 b, f32x4 c) {
    return __builtin_amdgcn_mfma_f32_16x16x32_bf16(
        __builtin_bit_cast(bf16x8, a), __builtin_bit_cast(bf16x8, b), c, 0, 0, 0);
}

__device__ __forceinline__ void gl_lds16(const void* g, void* l) {
    __builtin_amdgcn_global_load_lds(
        (const __attribute__((address_space(1))) unsigned int*)g,
        (__attribute__((address_space(3))) unsigned int*)l, 16, 0, 0);
}

// ---------------------------------------------------------------------------
// convX: fp32 -> bf16 elementwise, 8 elems/thread.
// ---------------------------------------------------------------------------
__global__ __launch_bounds__(256) void convX(const float* __restrict__ X,
                                             short* __restrict__ Xb)
{
    size_t i = ((size_t)blockIdx.x * 256 + threadIdx.x) * 8;
    float4 a = *(const float4*)(X + i);
    float4 b = *(const float4*)(X + i + 4);
    short8 s;
    s[0] = f2bf(a.x); s[1] = f2bf(a.y); s[2] = f2bf(a.z); s[3] = f2bf(a.w);
    s[4] = f2bf(b.x); s[5] = f2bf(b.y); s[6] = f2bf(b.z); s[7] = f2bf(b.w);
    *(short8*)(Xb + i) = s;
}

// ---------------------------------------------------------------------------
// convT: W fp32 [K=1024][N] -> Wt bf16 [N][1024]. 64x64 LDS tile transpose.
// ---------------------------------------------------------------------------
__global__ __launch_bounds__(256) void convT(const float* __restrict__ W,
                                             short* __restrict__ Wt, int N)
{
    __shared__ float L[64][65];
    const int kb = blockIdx.x * 64, nb = blockIdx.y * 64;
    const int tid = threadIdx.x;
#pragma unroll
    for (int it = 0; it < 4; it++) {
        int kk = it * 16 + (tid >> 4), c = (tid & 15) * 4;
        float4 v = *(const float4*)(W + (size_t)(kb + kk) * N + nb + c);
        L[c + 0][kk] = v.x; L[c + 1][kk] = v.y;
        L[c + 2][kk] = v.z; L[c + 3][kk] = v.w;
    }
    __syncthreads();
#pragma unroll
    for (int it = 0; it < 2; it++) {
        int n = it * 32 + (tid >> 3), ks = (tid & 7) * 8;
        short8 s;
#pragma unroll
        for (int j = 0; j < 8; j++) s[j] = f2bf(L[n][ks + j]);
        *(short8*)(Wt + (size_t)(nb + n) * 1024 + kb + ks) = s;
    }
}

// ---------------------------------------------------------------------------
// qkv GEMM: C = Xb @ Wqkv (via Wt [3072][1024]), M=4096,N=3072,K=1024.
// BM=64, BN=128, BK=64. grid (64,24) = 1536 blocks = 6/CU for latency hiding.
// LDS rows are 128 B -> XOR-swizzle (pre-swizzled global src, swizzled read)
// to kill the 16-way bank conflict. Single-buffer, 16 K-iterations.
// Per-wave output 32x64 (acc[2][4]). Fused RoPE / V-transpose epilogue.
// ---------------------------------------------------------------------------
__global__ __launch_bounds__(256, 6) void qkv_rope(
    const short* __restrict__ A, const short* __restrict__ Bt,
    const float* __restrict__ Sn, const float* __restrict__ Cs,
    short* __restrict__ Qo, short* __restrict__ Ko, short* __restrict__ Vt)
{
    __shared__ __align__(16) short LP[64 * 64 + 128 * 64];   // As | Bs, 24 KB
    short (*As)[64] = (short(*)[64])LP;
    short (*Bs)[64] = (short(*)[64])(LP + 64 * 64);

    const int bm = blockIdx.x, bn = blockIdx.y;
    const int tid = threadIdx.x;
    const int wv = tid >> 6, lane = tid & 63, g = lane >> 4, l16 = lane & 15;
    const int wr = wv >> 1, wc = wv & 1;
    const int sw = l16 & 7;

    f32x4 acc[2][4];
#pragma unroll
    for (int i = 0; i < 2; i++)
#pragma unroll
        for (int j = 0; j < 4; j++) acc[i][j] = (f32x4){0.f, 0.f, 0.f, 0.f};

    // staging: thread -> (row sr, 16B group c8); LDS dst linear, global src
    // column pre-swizzled by row&7 (attn-verified both-sides involution).
    const int sr = tid >> 3, c8 = tid & 7;
    const int gc8 = (c8 ^ (sr & 7)) << 3;
    const short* pA = A  + (size_t)(bm * 64  + sr) * 1024 + gc8;
    const short* pB = Bt + (size_t)(bn * 128 + sr) * 1024 + gc8;

    for (int k0 = 0; k0 < 1024; k0 += 64) {
        gl_lds16(pA + k0,             &As[sr][c8 << 3]);
        gl_lds16(pA + k0 + 32 * 1024, &As[32 + sr][c8 << 3]);
        gl_lds16(pB + k0,             &Bs[sr][c8 << 3]);
        gl_lds16(pB + k0 + 32 * 1024, &Bs[32 + sr][c8 << 3]);
        gl_lds16(pB + k0 + 64 * 1024, &Bs[64 + sr][c8 << 3]);
        gl_lds16(pB + k0 + 96 * 1024, &Bs[96 + sr][c8 << 3]);
        __syncthreads();
#pragma unroll
        for (int ks = 0; ks < 2; ks++) {
            short8 af[2], bfr[4];
#pragma unroll
            for (int mt = 0; mt < 2; mt++)
                af[mt]  = *(const short8*)&As[wr * 32 + mt * 16 + l16][((ks * 4 + g) ^ sw) << 3];
#pragma unroll
            for (int nt = 0; nt < 4; nt++)
                bfr[nt] = *(const short8*)&Bs[wc * 64 + nt * 16 + l16][((ks * 4 + g) ^ sw) << 3];
#pragma unroll
            for (int mt = 0; mt < 2; mt++)
#pragma unroll
                for (int nt = 0; nt < 4; nt++) acc[mt][nt] = mfma16(af[mt], bfr[nt], acc[mt][nt]);
        }
        __syncthreads();
    }

    if (bn >= 16) {
        // --------- V blocks: transpose 64(m) x 128(n) through LDS ---------
        short (*T)[72] = (short(*)[72])LP;       // 32 x 72 shorts = 4.6 KB
        const int b  = bm >> 5;                  // (bm*64)>>11, uniform
        const int t0 = (bm * 64) & 2047;
        const int nbase = (bn - 16) * 128;
#pragma unroll
        for (int ch = 0; ch < 4; ++ch) {
            __syncthreads();                     // prev chunk's reads done
            if (wc == (ch >> 1)) {
#pragma unroll
                for (int ntl = 0; ntl < 2; ++ntl) {
                    int nt = (ch & 1) * 2 + ntl;
#pragma unroll
                    for (int mt = 0; mt < 2; ++mt)
#pragma unroll
                        for (int r = 0; r < 4; ++r)
                            T[ntl * 16 + l16][wr * 32 + mt * 16 + g * 4 + r] =
                                f2bf(acc[mt][nt][r]);
                }
            }
            __syncthreads();
            // 32 rows x 64 cols, 256 threads -> one short8 each, coalesced
            int row = tid >> 3, cc8 = (tid & 7) * 8;
            int nn = nbase + ch * 32 + row;
            int h = nn >> 6, d = nn & 63;
            short8 v0 = *(const short8*)&T[row][cc8];
            size_t base = (((size_t)(b * 16 + h) * 64 + d) << 11) + t0 + cc8;
            *(short8*)(Vt + base) = v0;
        }
    } else {
        // --------- Q/K blocks: RoPE epilogue ---------
#pragma unroll
        for (int mt = 0; mt < 2; mt++)
#pragma unroll
            for (int nt = 0; nt < 4; nt++)
#pragma unroll
                for (int r = 0; r < 4; r++) {
                    int m = bm * 64 + wr * 32 + mt * 16 + g * 4 + r;
                    int n = bn * 128 + wc * 64 + nt * 16 + l16;
                    float val = acc[mt][nt][r];
                    float partner = __shfl_xor(val, 1, 64);
                    int b = m >> 11, t = m & 2047;
                    int sec = n >> 10, nn = n & 1023;
                    int h = nn >> 6, d = nn & 63;
                    float sv = Sn[t * 64 + d], cv = Cs[t * 64 + d];
                    float ro = (d & 1) ? fmaf(val, cv, partner * sv)
                                       : fmaf(val, cv, -partner * sv);
                    short* dst = (sec == 0) ? Qo : Ko;
                    dst[(((size_t)(b * 16 + h) << 11) + t) * 64 + d] = f2bf(ro);
                }
    }
}

// ---------------------------------------------------------------------------
// Kernel 2: causal flash attention (unchanged — verified).
// ---------------------------------------------------------------------------
__global__ __launch_bounds__(256, 4) void attn(
    const short* __restrict__ Q, const short* __restrict__ K,
    const short* __restrict__ V, short* __restrict__ Y)
{
    __shared__ __align__(16) short Ks[2][64][64];
    __shared__ __align__(16) short Vs[2][64][64];
    __shared__ __align__(16) short Pl[4][16][64];

    const int id = blockIdx.y * gridDim.x + blockIdx.x;
    const int bh = id >> 5;
    const int qi = ((id & 31) + ((id >> 8) << 3)) & 31;
    const int tid = threadIdx.x, wv = tid >> 6, lane = tid & 63;
    const int g = lane >> 4, l16 = lane & 15;
    const int q0w = qi * 64 + wv * 16;
    const short* Qb = Q + (size_t)bh * Tt * 64;
    const short* Kb = K + (size_t)bh * Tt * 64;
    const short* Vb = V + (size_t)bh * 64 * Tt;

    const int rj = lane >> 3, cc = lane & 7, gc = cc ^ rj;

    auto stage = [&](int s, int buf) {
        int k0s = s * 64;
#pragma unroll
        for (int j = 0; j < 2; j++) {
            int row = wv * 16 + j * 8 + rj;
            gl_lds16(Kb + (size_t)(k0s + row) * 64 + gc * 8, &Ks[buf][row][cc << 3]);
        }
#pragma unroll
        for (int j = 0; j < 2; j++) {
            int row = wv * 16 + j * 8 + rj;
            gl_lds16(Vb + (size_t)row * Tt + k0s + gc * 8, &Vs[buf][row][cc << 3]);
        }
    };

    short8 qf[2];
#pragma unroll
    for (int ss = 0; ss < 2; ss++)
        qf[ss] = *(const short8*)(Qb + (size_t)(q0w + l16) * 64 + ss * 32 + g * 8);

    f32x4 o[4];
#pragma unroll
    for (int nt = 0; nt < 4; nt++) o[nt] = (f32x4){0.f, 0.f, 0.f, 0.f};
    float lsum[4] = {0.f, 0.f, 0.f, 0.f};

    const int nsteps = qi + 1;
    const int sw = l16 & 7;

    stage(0, 0);
    __syncthreads();

    for (int s = 0; s < nsteps; ++s) {
        if (s + 1 < nsteps) stage(s + 1, (s + 1) & 1);
        const int kb = s & 1, k0 = s * 64;

        f32x4 S[4];
#pragma unroll
        for (int t = 0; t < 4; t++) {
            S[t] = (f32x4){0.f, 0.f, 0.f, 0.f};
#pragma unroll
            for (int ss = 0; ss < 2; ss++) {
                short8 kf = *(const short8*)&Ks[kb][t * 16 + l16][((ss * 4 + g) ^ sw) << 3];
                S[t] = mfma16(qf[ss], kf, S[t]);
            }
        }

        float p[4][4];
        if (s < nsteps - 1) {
#pragma unroll
            for (int t = 0; t < 4; t++)
#pragma unroll
                for (int r = 0; r < 4; r++)
                    p[t][r] = __expf(fmaf(S[t][r], 0.125f, -10.f));
        } else {
#pragma unroll
            for (int t = 0; t < 4; t++)
#pragma unroll
                for (int r = 0; r < 4; r++) {
                    int key = k0 + t * 16 + l16, qq = q0w + g * 4 + r;
                    p[t][r] = (key <= qq) ? __expf(fmaf(S[t][r], 0.125f, -10.f)) : 0.f;
                }
        }
#pragma unroll
        for (int r = 0; r < 4; r++)
            lsum[r] += (p[0][r] + p[1][r]) + (p[2][r] + p[3][r]);

#pragma unroll
        for (int t = 0; t < 4; t++)
#pragma unroll
            for (int r = 0; r < 4; r++) {
                int row = g * 4 + r, c = t * 16 + l16;
                Pl[wv][row][(((c >> 3) ^ (row & 7)) << 3) | (c & 7)] = f2bf(p[t][r]);
            }
        asm volatile("" ::: "memory");
        short8 pf[2];
#pragma unroll
        for (int ks = 0; ks < 2; ks++)
            pf[ks] = *(const short8*)&Pl[wv][l16][((ks * 4 + g) ^ sw) << 3];
#pragma unroll
        for (int nt = 0; nt < 4; nt++)
#pragma unroll
            for (int ks = 0; ks < 2; ks++) {
                short8 vf = *(const short8*)&Vs[kb][nt * 16 + l16][((ks * 4 + g) ^ sw) << 3];
                o[nt] = mfma16(pf[ks], vf, o[nt]);
            }
        __syncthreads();
    }

    float inv[4];
#pragma unroll
    for (int r = 0; r < 4; r++) {
        float t = lsum[r];
        t += __shfl_xor(t, 1, 64);
        t += __shfl_xor(t, 2, 64);
        t += __shfl_xor(t, 4, 64);
        t += __shfl_xor(t, 8, 64);
        inv[r] = 1.0f / t;
    }
    const int b = bh >> 4, h = bh & 15;
#pragma unroll
    for (int nt = 0; nt < 4; nt++)
#pragma unroll
        for (int r = 0; r < 4; r++) {
            int qq = q0w + g * 4 + r, d = nt * 16 + l16;
            Y[((size_t)(b * Tt + qq)) * DIMc + h * 64 + d] = f2bf(o[nt][r] * inv[r]);
        }
}

// ---------------------------------------------------------------------------
// proj GEMM: out = Y @ Wproj (via Wt [1024][1024]), fp32 out.
// BM=BN=64, BK=64. grid (64,16) = 1024 blocks = 4/CU (was 1/CU).
// ---------------------------------------------------------------------------
__global__ __launch_bounds__(256, 4) void proj(
    const short* __restrict__ A, const short* __restrict__ Bt, float* __restrict__ O)
{
    __shared__ __align__(16) short As[64][64];
    __shared__ __align__(16) short Bs[64][64];
    const int bm = blockIdx.x, bn = blockIdx.y;
    const int tid = threadIdx.x;
    const int wv = tid >> 6, lane = tid & 63, g = lane >> 4, l16 = lane & 15;
    const int wr = wv >> 1, wc = wv & 1;
    const int sw = l16 & 7;

    f32x4 acc[2][2];
#pragma unroll
    for (int i = 0; i < 2; i++)
#pragma unroll
        for (int j = 0; j < 2; j++) acc[i][j] = (f32x4){0.f, 0.f, 0.f, 0.f};

    const int sr = tid >> 3, c8 = tid & 7;
    const int gc8 = (c8 ^ (sr & 7)) << 3;
    const short* pA = A  + (size_t)(bm * 64 + sr) * 1024 + gc8;
    const short* pB = Bt + (size_t)(bn * 64 + sr) * 1024 + gc8;

    for (int k0 = 0; k0 < 1024; k0 += 64) {
        gl_lds16(pA + k0,             &As[sr][c8 << 3]);
        gl_lds16(pA + k0 + 32 * 1024, &As[32 + sr][c8 << 3]);
        gl_lds16(pB + k0,             &Bs[sr][c8 << 3]);
        gl_lds16(pB + k0 + 32 * 1024, &Bs[32 + sr][c8 << 3]);
        __syncthreads();
#pragma unroll
        for (int ks = 0; ks < 2; ks++) {
            short8 af[2], bfr[2];
#pragma unroll
            for (int mt = 0; mt < 2; mt++)
                af[mt]  = *(const short8*)&As[wr * 32 + mt * 16 + l16][((ks * 4 + g) ^ sw) << 3];
#pragma unroll
            for (int nt = 0; nt < 2; nt++)
                bfr[nt] = *(const short8*)&Bs[wc * 32 + nt * 16 + l16][((ks * 4 + g) ^ sw) << 3];
#pragma unroll
            for (int mt = 0; mt < 2; mt++)
#pragma unroll
                for (int nt = 0; nt < 2; nt++) acc[mt][nt] = mfma16(af[mt], bfr[nt], acc[mt][nt]);
        }
        __syncthreads();
    }

#pragma unroll
    for (int mt = 0; mt < 2; mt++)
#pragma unroll
        for (int nt = 0; nt < 2; nt++)
#pragma unroll
            for (int r = 0; r < 4; r++) {
                int m = bm * 64 + wr * 32 + mt * 16 + g * 4 + r;
                int n = bn * 64 + wc * 32 + nt * 16 + l16;
                O[(size_t)m * 1024 + n] = acc[mt][nt][r];
            }
}

// ---------------------------------------------------------------------------
extern "C" void kernel_launch(void* const* d_in, const int* in_sizes, int n_in,
                              void* d_out, int out_size, void* d_ws, size_t ws_size,
                              hipStream_t stream)
{
    const float* x     = (const float*)d_in[0];
    const float* sn    = (const float*)d_in[1];
    const float* cs    = (const float*)d_in[2];
    const float* wqkv  = (const float*)d_in[3];
    const float* wproj = (const float*)d_in[4];
    float* out = (float*)d_out;

    char* ws = (char*)d_ws;
    const size_t MB = 1024 * 1024;
    short* q   = (short*)(ws);            // 8 MB
    short* k   = (short*)(ws + 8  * MB);  // 8 MB
    short* vt  = (short*)(ws + 16 * MB);  // 8 MB
    short* y   = (short*)(ws + 24 * MB);  // 8 MB
    short* xb  = (short*)(ws + 32 * MB);  // 8 MB
    short* wqt = (short*)(ws + 40 * MB);  // 6 MB
    short* wpt = (short*)(ws + 46 * MB);  // 2 MB

    convX<<<2048, 256, 0, stream>>>(x, xb);
    convT<<<dim3(16, 48), 256, 0, stream>>>(wqkv, wqt, 3072);
    convT<<<dim3(16, 16), 256, 0, stream>>>(wproj, wpt, 1024);
    qkv_rope<<<dim3(64, 24), 256, 0, stream>>>(xb, wqt, sn, cs, q, k, vt);
    attn<<<dim3(Tt / 64, Bb * NHh), 256, 0, stream>>>(q, k, vt, y);
    proj<<<dim3(64, 16), 256, 0, stream>>>(y, wpt, out);
}